// Round 1
// baseline (541.830 us; speedup 1.0000x reference)
//
#include <hip/hip_runtime.h>
#include <stdint.h>

#define TK_F       4096
#define TK_THREADS 256
#define TK_EPT     16          // elements per thread
#define TK_NBINS   2048        // top-11-bit histogram
#define TK_CAP     1024        // candidate list capacity (threshold bin)

// order-preserving float->uint transform: larger float <=> larger uint
__device__ __forceinline__ unsigned int tk_f2u(unsigned int b) {
    return b ^ ((unsigned int)(((int)b) >> 31) | 0x80000000u);
}
__device__ __forceinline__ unsigned int tk_u2f(unsigned int u) {
    return u ^ ((~(unsigned int)(((int)u) >> 31)) | 0x80000000u);
}

__global__ __launch_bounds__(TK_THREADS, 4)
void tk_topk_mask(const float* __restrict__ x, const int* __restrict__ kp,
                  float* __restrict__ out, int B)
{
    __shared__ unsigned int hist[TK_NBINS];
    __shared__ unsigned int cand[TK_CAP];
    __shared__ unsigned int waveTot[TK_THREADS / 64];
    __shared__ unsigned int sh_cnt;
    __shared__ int          sh_b;
    __shared__ unsigned int sh_cum;
    __shared__ unsigned int sh_T, sh_g, sh_e;

    const int tid = threadIdx.x;
    const int row = blockIdx.x;
    if (row >= B) return;
    const unsigned int k = (unsigned int)kp[0];

    const unsigned int* xr  = (const unsigned int*)(x + (size_t)row * TK_F);
    unsigned int*       orow = (unsigned int*)(out + (size_t)row * TK_F);

    // clear LDS state
    for (int i = tid; i < TK_NBINS; i += TK_THREADS) hist[i] = 0u;
    if (tid == 0) { sh_cnt = 0u; sh_b = -1; }

    // load 16 elements (4x uint4, coalesced), keep in registers as orderable uints
    unsigned int u[TK_EPT];
    const uint4* xv = (const uint4*)xr;
    #pragma unroll
    for (int v = 0; v < 4; ++v) {
        uint4 q = xv[tid + v * TK_THREADS];
        u[v*4+0] = tk_f2u(q.x);
        u[v*4+1] = tk_f2u(q.y);
        u[v*4+2] = tk_f2u(q.z);
        u[v*4+3] = tk_f2u(q.w);
    }
    __syncthreads();   // hist cleared

    // 11-bit histogram (LDS atomics; max-bin occupancy ~2% of row -> low contention)
    #pragma unroll
    for (int e = 0; e < TK_EPT; ++e)
        atomicAdd(&hist[u[e] >> 21], 1u);
    __syncthreads();

    // suffix scan: thread t owns bins [8t, 8t+8)
    unsigned int hbin[8];
    unsigned int s = 0;
    const int base = tid * 8;
    #pragma unroll
    for (int j = 0; j < 8; ++j) { hbin[j] = hist[base + j]; s += hbin[j]; }

    // wave-level inclusive suffix sum of s
    unsigned int acc = s;
    const int lane = tid & 63;
    #pragma unroll
    for (int d = 1; d < 64; d <<= 1) {
        unsigned int v = (unsigned int)__shfl_down((int)acc, d, 64);
        if (lane + d < 64) acc += v;
    }
    const int wid = tid >> 6;
    if (lane == 0) waveTot[wid] = acc;     // lane0 suffix == wave total
    __syncthreads();
    unsigned int later = 0;
    #pragma unroll
    for (int w = 0; w < TK_THREADS / 64; ++w)
        if (w > wid) later += waveTot[w];

    // count of elements in bins strictly above my highest bin
    unsigned int run = later + (acc - s);
    #pragma unroll
    for (int j = 7; j >= 0; --j) {
        unsigned int h = hbin[j];
        if (run < k && run + h >= k) { sh_b = base + j; sh_cum = run; }
        run += h;
    }
    __syncthreads();

    const int b = sh_b;
    if (b < 0) {
        // k >= row length: everything passes through
        #pragma unroll
        for (int v = 0; v < 4; ++v) {
            uint4 q;
            q.x = tk_u2f(u[v*4+0]); q.y = tk_u2f(u[v*4+1]);
            q.z = tk_u2f(u[v*4+2]); q.w = tk_u2f(u[v*4+3]);
            ((uint4*)orow)[tid + v * TK_THREADS] = q;
        }
        return;
    }
    const unsigned int cum = sh_cum;          // # elements strictly above bin b

    // collect candidates (elements whose top-11 bits == b)
    #pragma unroll
    for (int e = 0; e < TK_EPT; ++e) {
        if ((int)(u[e] >> 21) == b) {
            unsigned int p = atomicAdd(&sh_cnt, 1u);
            if (p < TK_CAP) cand[p] = u[e];
        }
    }
    __syncthreads();

    const unsigned int L = (sh_cnt < TK_CAP) ? sh_cnt : TK_CAP;
    const unsigned int r = k - cum;           // rank needed inside bin b (1-based)
    for (unsigned int j = tid; j < L; j += TK_THREADS) {
        unsigned int uj = cand[j];
        unsigned int g = 0, eq = 0;
        for (unsigned int i = 0; i < L; ++i) {
            unsigned int ui = cand[i];        // broadcast read
            g  += (ui > uj)  ? 1u : 0u;
            eq += (ui == uj) ? 1u : 0u;
        }
        if (g < r && g + eq >= r) { sh_T = uj; sh_g = g; sh_e = eq; }
    }
    __syncthreads();

    const unsigned int T  = sh_T;
    const unsigned int re = r - sh_g;         // # equal-to-T elements to include
    const unsigned int ce = sh_e;             // total equal-to-T elements in row
    const bool easy = (ce == re);             // no tie at the cut (overwhelmingly common)

    #pragma unroll
    for (int v = 0; v < 4; ++v) {
        uint4 q;
        #pragma unroll
        for (int j = 0; j < 4; ++j) {
            unsigned int uu  = u[v*4+j];
            unsigned int val = 0u;
            if (uu > T) {
                val = tk_u2f(uu);
            } else if (uu == T) {
                if (easy) {
                    val = tk_u2f(uu);
                } else {
                    // rare: duplicated value straddles the cut -> lowest indices win.
                    int idx = (tid + v * TK_THREADS) * 4 + j;
                    unsigned int cnt = 0;
                    for (int i = 0; i < idx; ++i)
                        cnt += (tk_f2u(xr[i]) == T) ? 1u : 0u;
                    if (cnt < re) val = tk_u2f(uu);
                }
            }
            (&q.x)[j] = val;
        }
        ((uint4*)orow)[tid + v * TK_THREADS] = q;
    }
}

extern "C" void kernel_launch(void* const* d_in, const int* in_sizes, int n_in,
                              void* d_out, int out_size, void* d_ws, size_t ws_size,
                              hipStream_t stream) {
    const float* x  = (const float*)d_in[0];
    const int*   kp = (const int*)d_in[1];
    float*       out = (float*)d_out;
    const int B = in_sizes[0] / TK_F;
    hipLaunchKernelGGL(tk_topk_mask, dim3(B), dim3(TK_THREADS), 0, stream,
                       x, kp, out, B);
}